// Round 9
// baseline (1301.996 us; speedup 1.0000x reference)
//
#include <hip/hip_runtime.h>
#include <hip/hip_bf16.h>
#include <math.h>

// ---------------------------------------------------------------------------
// AttentionEncoderModel on MI355X — round 9: LDS-staged conv tower.
// bf16x3 MFMA GEMMs + fused attention unchanged from validated round 8.
// ---------------------------------------------------------------------------

#define DMODEL 256
#define SEQ    512

typedef __attribute__((ext_vector_type(8))) short bf16x8;
typedef __attribute__((ext_vector_type(4))) float f32x4;

static __device__ __forceinline__ unsigned short f2bf(float v) {
  __hip_bfloat16 h = __float2bfloat16(v);
  return *reinterpret_cast<unsigned short*>(&h);
}
static __device__ __forceinline__ float bf2f(unsigned short u) {
  __hip_bfloat16 h;
  *reinterpret_cast<unsigned short*>(&h) = u;
  return __bfloat162float(h);
}
static __device__ __forceinline__ void split2(float v, unsigned short& h,
                                              unsigned short& l) {
  h = f2bf(v);
  l = f2bf(v - bf2f(h));
}

// ---------------- conv1 (LDS): 3->16, 96x120 -> 48x60 -----------------------
// grid = 1024 images x 12 bands (4 output rows each), 256 threads.
__global__ __launch_bounds__(256) void conv1_lds_kernel(
    const float* __restrict__ in, const float* __restrict__ w,
    const float* __restrict__ bias, float* __restrict__ out) {
  __shared__ float wsm[768];                 // 16 oc * 3 ic * 16
  __shared__ float tin[3][10][124];          // rows gy0..gy0+9, cols -1..120
  int t = threadIdx.x;
  int band = blockIdx.x % 12;
  int n    = blockIdx.x / 12;
  int oy0 = band * 4;
  int gy0 = oy0 * 2 - 1;
  for (int i = t; i < 768; i += 256) wsm[i] = w[i];
  for (int idx = t; idx < 3 * 10 * 124; idx += 256) {
    int c  = idx % 124;
    int r  = (idx / 124) % 10;
    int ic = idx / 1240;
    int gy = gy0 + r, gx = c - 1;
    float v = 0.f;
    if (gx >= 0 && gx < 120 && gy >= 0 && gy < 96)
      v = in[((n * 3 + ic) * 96 + gy) * 120 + gx];
    tin[ic][r][c] = v;
  }
  __syncthreads();
  if (t >= 240) return;
  int ox = t % 60;
  int ry = t / 60;                            // 0..3
  float win[3][16];
  #pragma unroll
  for (int ic = 0; ic < 3; ic++)
    #pragma unroll
    for (int r = 0; r < 4; r++) {
      float2 a = *(float2*)&tin[ic][ry * 2 + r][2 * ox];
      float2 b = *(float2*)&tin[ic][ry * 2 + r][2 * ox + 2];
      win[ic][r * 4 + 0] = a.x; win[ic][r * 4 + 1] = a.y;
      win[ic][r * 4 + 2] = b.x; win[ic][r * 4 + 3] = b.y;
    }
  #pragma unroll
  for (int oc = 0; oc < 16; oc++) {
    float acc = bias[oc];
    #pragma unroll
    for (int ic = 0; ic < 3; ic++) {
      const float* wp = &wsm[oc * 48 + ic * 16];
      #pragma unroll
      for (int k = 0; k < 16; k++) acc = fmaf(win[ic][k], wp[k], acc);
    }
    out[((n * 16 + oc) * 48 + oy0 + ry) * 60 + ox] = fmaxf(acc, 0.f);
  }
}

// ---------------- conv2 (LDS): 16->16, 48x60 -> 24x30 -----------------------
// grid = 1024 images x 6 bands (4 output rows), 256 threads;
// thread = (ox 0..29, ry 0..3, oc-half 0..1) -> 8 oc each; 240 active.
__global__ __launch_bounds__(256) void conv2_lds_kernel(
    const float* __restrict__ in, const float* __restrict__ w,
    const float* __restrict__ bias, float* __restrict__ out) {
  __shared__ float wsm[4096];                // 16*16*16
  __shared__ float tin[16][10][64];          // rows gy0..+9, cols -1..60 (pad)
  int t = threadIdx.x;
  int band = blockIdx.x % 6;
  int n    = blockIdx.x / 6;
  int oy0 = band * 4;
  int gy0 = oy0 * 2 - 1;
  for (int i = t; i < 4096; i += 256) wsm[i] = w[i];
  for (int idx = t; idx < 16 * 10 * 64; idx += 256) {
    int c  = idx & 63;
    int r  = (idx >> 6) % 10;
    int ic = idx / 640;
    int gy = gy0 + r, gx = c - 1;
    float v = 0.f;
    if (gx >= 0 && gx < 60 && gy >= 0 && gy < 48)
      v = in[((n * 16 + ic) * 48 + gy) * 60 + gx];
    tin[ic][r][c] = v;
  }
  __syncthreads();
  if (t >= 240) return;
  int ox = t % 30;
  int ry = (t / 30) % 4;
  int oh = t / 120;                           // oc half
  float acc[8];
  #pragma unroll
  for (int i = 0; i < 8; i++) acc[i] = bias[oh * 8 + i];
  for (int ic = 0; ic < 16; ic++) {
    float win[16];
    #pragma unroll
    for (int r = 0; r < 4; r++) {
      float2 a = *(float2*)&tin[ic][ry * 2 + r][2 * ox];
      float2 b = *(float2*)&tin[ic][ry * 2 + r][2 * ox + 2];
      win[r * 4 + 0] = a.x; win[r * 4 + 1] = a.y;
      win[r * 4 + 2] = b.x; win[r * 4 + 3] = b.y;
    }
    #pragma unroll
    for (int oc = 0; oc < 8; oc++) {
      const float* wp = &wsm[((oh * 8 + oc) * 16 + ic) * 16];
      float a = acc[oc];
      #pragma unroll
      for (int k = 0; k < 16; k++) a = fmaf(win[k], wp[k], a);
      acc[oc] = a;
    }
  }
  #pragma unroll
  for (int oc = 0; oc < 8; oc++)
    out[((n * 16 + oh * 8 + oc) * 24 + oy0 + ry) * 30 + ox] = fmaxf(acc[oc], 0.f);
}

// ---------------- conv3 (LDS): 16->16, 24x30 -> 12x15 -----------------------
// grid = 1024 images, 192 threads; thread t<180 = (ox 0..14, oy 0..11), 16 oc.
__global__ __launch_bounds__(192) void conv3_lds_kernel(
    const float* __restrict__ in, const float* __restrict__ w,
    const float* __restrict__ bias, float* __restrict__ out) {
  __shared__ float wsm[4096];
  __shared__ float tin[16][26][32];          // rows -1..24, cols -1..30 (pad)
  int t = threadIdx.x;
  int n = blockIdx.x;
  for (int i = t; i < 4096; i += 192) wsm[i] = w[i];
  for (int idx = t; idx < 16 * 26 * 32; idx += 192) {
    int c  = idx & 31;
    int r  = (idx >> 5) % 26;
    int ic = idx / 832;
    int gy = r - 1, gx = c - 1;
    float v = 0.f;
    if (gx >= 0 && gx < 30 && gy >= 0 && gy < 24)
      v = in[((n * 16 + ic) * 24 + gy) * 30 + gx];
    tin[ic][r][c] = v;
  }
  __syncthreads();
  if (t >= 180) return;
  int ox = t % 15;
  int oy = t / 15;                            // 0..11
  float acc[16];
  #pragma unroll
  for (int i = 0; i < 16; i++) acc[i] = bias[i];
  for (int ic = 0; ic < 16; ic++) {
    float win[16];
    #pragma unroll
    for (int r = 0; r < 4; r++) {
      float2 a = *(float2*)&tin[ic][oy * 2 + r][2 * ox];
      float2 b = *(float2*)&tin[ic][oy * 2 + r][2 * ox + 2];
      win[r * 4 + 0] = a.x; win[r * 4 + 1] = a.y;
      win[r * 4 + 2] = b.x; win[r * 4 + 3] = b.y;
    }
    #pragma unroll
    for (int oc = 0; oc < 16; oc++) {
      const float* wp = &wsm[(oc * 16 + ic) * 16];
      float a = acc[oc];
      #pragma unroll
      for (int k = 0; k < 16; k++) a = fmaf(win[k], wp[k], a);
      acc[oc] = a;
    }
  }
  #pragma unroll
  for (int oc = 0; oc < 16; oc++)
    out[((n * 16 + oc) * 12 + oy) * 15 + ox] = fmaxf(acc[oc], 0.f);
}

// ---------------- weight transpose + bf16 split -----------------------------
__global__ __launch_bounds__(256) void tcvt_kernel(
    const float* __restrict__ W, unsigned short* __restrict__ Th,
    unsigned short* __restrict__ Tl, int K, int N) {
  __shared__ float lds[32][33];
  int t = threadIdx.x;
  int kt = blockIdx.x, nt = blockIdx.y, b = blockIdx.z;
  const float* Wb = W + (size_t)b * K * N;
  unsigned short* Thb = Th + (size_t)b * K * N;
  unsigned short* Tlb = Tl + (size_t)b * K * N;
  int c = t & 31, r0 = (t >> 5) * 4;
  #pragma unroll
  for (int i = 0; i < 4; i++)
    lds[r0 + i][c] = Wb[(size_t)(kt * 32 + r0 + i) * N + nt * 32 + c];
  __syncthreads();
  #pragma unroll
  for (int i = 0; i < 4; i++) {
    float v = lds[c][r0 + i];
    unsigned short h, l;
    split2(v, h, l);
    size_t o = (size_t)(nt * 32 + r0 + i) * K + kt * 32 + c;
    Thb[o] = h;
    Tlb[o] = l;
  }
}

// ---------------- fp32 -> bf16 hi/lo pair conversion ------------------------
__global__ __launch_bounds__(256) void cvtpair_kernel(
    const float4* __restrict__ in, unsigned short* __restrict__ oh,
    unsigned short* __restrict__ ol) {
  int i = blockIdx.x * 256 + threadIdx.x;
  float4 v = in[i];
  ushort4 H, L;
  split2(v.x, H.x, L.x);
  split2(v.y, H.y, L.y);
  split2(v.z, H.z, L.z);
  split2(v.w, H.w, L.w);
  *(ushort4*)&oh[i * 4] = H;
  *(ushort4*)&ol[i * 4] = L;
}

// ---------------- bf16x3 MFMA GEMM (validated round 8) ----------------------
template <int EPI>
__global__ __launch_bounds__(256) void gemm_mfma_kernel(
    const unsigned short* __restrict__ Ah, const unsigned short* __restrict__ Al,
    const unsigned short* __restrict__ Bh, const unsigned short* __restrict__ Bl,
    const float* __restrict__ bias, float* __restrict__ C,
    unsigned short* __restrict__ Ch, unsigned short* __restrict__ Cl,
    int M, int N, int K, int klen) {
  __shared__ unsigned short As[2][128 * 40];
  __shared__ unsigned short Bs[2][128 * 40];
  int t = threadIdx.x;
  int n0 = blockIdx.x * 128, m0 = blockIdx.y * 128;
  int kb = blockIdx.z * klen;
  int w = t >> 6, l = t & 63;
  int wr = w >> 1, wc = w & 1;
  int fr = l & 15, fq = l >> 4;
  f32x4 acc[4][4];
  #pragma unroll
  for (int i = 0; i < 4; i++)
    #pragma unroll
    for (int j = 0; j < 4; j++) acc[i][j] = (f32x4){0.f, 0.f, 0.f, 0.f};

  for (int kt = 0; kt < klen; kt += 32) {
    int kg = kb + kt;
    #pragma unroll
    for (int s = 0; s < 2; s++) {
      int q = t + 256 * s;
      int row = q >> 2, ko = (q & 3) << 3;
      *(int4*)&As[0][row * 40 + ko] =
          *(const int4*)&Ah[(size_t)(m0 + row) * K + kg + ko];
      *(int4*)&As[1][row * 40 + ko] =
          *(const int4*)&Al[(size_t)(m0 + row) * K + kg + ko];
      *(int4*)&Bs[0][row * 40 + ko] =
          *(const int4*)&Bh[(size_t)(n0 + row) * K + kg + ko];
      *(int4*)&Bs[1][row * 40 + ko] =
          *(const int4*)&Bl[(size_t)(n0 + row) * K + kg + ko];
    }
    __syncthreads();
    bf16x8 ah[4], al4[4], bh4[4], bl4[4];
    #pragma unroll
    for (int fm = 0; fm < 4; fm++) {
      int ro = (wr * 64 + fm * 16 + fr) * 40 + fq * 8;
      ah[fm]  = *(const bf16x8*)&As[0][ro];
      al4[fm] = *(const bf16x8*)&As[1][ro];
    }
    #pragma unroll
    for (int fn = 0; fn < 4; fn++) {
      int ro = (wc * 64 + fn * 16 + fr) * 40 + fq * 8;
      bh4[fn] = *(const bf16x8*)&Bs[0][ro];
      bl4[fn] = *(const bf16x8*)&Bs[1][ro];
    }
    #pragma unroll
    for (int fm = 0; fm < 4; fm++)
      #pragma unroll
      for (int fn = 0; fn < 4; fn++) {
        acc[fm][fn] = __builtin_amdgcn_mfma_f32_16x16x32_bf16(
            ah[fm], bh4[fn], acc[fm][fn], 0, 0, 0);
        acc[fm][fn] = __builtin_amdgcn_mfma_f32_16x16x32_bf16(
            ah[fm], bl4[fn], acc[fm][fn], 0, 0, 0);
        acc[fm][fn] = __builtin_amdgcn_mfma_f32_16x16x32_bf16(
            al4[fm], bh4[fn], acc[fm][fn], 0, 0, 0);
      }
    __syncthreads();
  }

  #pragma unroll
  for (int fm = 0; fm < 4; fm++) {
    int rbase = m0 + wr * 64 + fm * 16 + fq * 4;
    #pragma unroll
    for (int fn = 0; fn < 4; fn++) {
      int col = n0 + wc * 64 + fn * 16 + fr;
      #pragma unroll
      for (int i = 0; i < 4; i++) {
        int m = rbase + i;
        float v = acc[fm][fn][i];
        if (EPI == 2) {
          atomicAdd(&C[(size_t)m * N + col], v);
        } else if (EPI == 0) {
          C[(size_t)m * N + col] = v + bias[col];
        } else {
          float g = v + bias[col];
          g = 0.5f * g * (1.f + erff(g * 0.70710678118654752f));
          unsigned short hh, ll;
          split2(g, hh, ll);
          Ch[(size_t)m * N + col] = hh;
          Cl[(size_t)m * N + col] = ll;
        }
      }
    }
  }
}

// ---------------- glue -------------------------------------------------------
__global__ __launch_bounds__(256) void initpre4_kernel(
    float4* __restrict__ C, const float4* __restrict__ bias,
    const float4* __restrict__ pos) {
  int i = blockIdx.x * 256 + threadIdx.x;
  int n4 = i & 63;
  int m = i >> 6;
  float4 b = bias[n4], p = pos[(m & (SEQ - 1)) * 64 + n4];
  C[i] = make_float4(b.x + p.x, b.y + p.y, b.z + p.z, b.w + p.w);
}

__global__ __launch_bounds__(256) void addbias4_kernel(
    float4* __restrict__ C, const float4* __restrict__ bias) {
  int i = blockIdx.x * 256 + threadIdx.x;
  float4 v = C[i], b = bias[i & 63];
  v.x += b.x; v.y += b.y; v.z += b.z; v.w += b.w;
  C[i] = v;
}

// ---------------- LayerNorm variants ----------------------------------------
__global__ __launch_bounds__(256) void ln1_bf_kernel(
    const float* __restrict__ x, const float* __restrict__ g,
    const float* __restrict__ b, unsigned short* __restrict__ oh,
    unsigned short* __restrict__ ol) {
  int lane = threadIdx.x & 63;
  int wid  = threadIdx.x >> 6;
  int row  = blockIdx.x * 4 + wid;
  const float* xr = x + row * DMODEL;
  float v[4];
  #pragma unroll
  for (int i = 0; i < 4; i++) v[i] = xr[lane + 64 * i];
  float s = v[0] + v[1] + v[2] + v[3];
  #pragma unroll
  for (int o = 32; o >= 1; o >>= 1) s += __shfl_xor(s, o);
  float mu = s * (1.f / 256.f);
  float sq = 0.f;
  #pragma unroll
  for (int i = 0; i < 4; i++) { float d = v[i] - mu; sq = fmaf(d, d, sq); }
  #pragma unroll
  for (int o = 32; o >= 1; o >>= 1) sq += __shfl_xor(sq, o);
  float rs = rsqrtf(sq * (1.f / 256.f) + 1e-5f);
  #pragma unroll
  for (int i = 0; i < 4; i++) {
    int c = lane + 64 * i;
    float vv = (v[i] - mu) * rs * g[c] + b[c];
    unsigned short h, l;
    split2(vv, h, l);
    oh[row * DMODEL + c] = h;
    ol[row * DMODEL + c] = l;
  }
}

__global__ __launch_bounds__(256) void ln2_bf_kernel(
    float* __restrict__ x, const float* __restrict__ g,
    const float* __restrict__ b, unsigned short* __restrict__ oh,
    unsigned short* __restrict__ ol) {
  int lane = threadIdx.x & 63;
  int wid  = threadIdx.x >> 6;
  int row  = blockIdx.x * 4 + wid;
  float* xr = x + row * DMODEL;
  float v[4];
  #pragma unroll
  for (int i = 0; i < 4; i++) v[i] = xr[lane + 64 * i];
  float s = v[0] + v[1] + v[2] + v[3];
  #pragma unroll
  for (int o = 32; o >= 1; o >>= 1) s += __shfl_xor(s, o);
  float mu = s * (1.f / 256.f);
  float sq = 0.f;
  #pragma unroll
  for (int i = 0; i < 4; i++) { float d = v[i] - mu; sq = fmaf(d, d, sq); }
  #pragma unroll
  for (int o = 32; o >= 1; o >>= 1) sq += __shfl_xor(sq, o);
  float rs = rsqrtf(sq * (1.f / 256.f) + 1e-5f);
  #pragma unroll
  for (int i = 0; i < 4; i++) {
    int c = lane + 64 * i;
    float vv = (v[i] - mu) * rs * g[c] + b[c];
    xr[c] = vv;
    unsigned short h, l;
    split2(vv, h, l);
    oh[row * DMODEL + c] = h;
    ol[row * DMODEL + c] = l;
  }
}

// ---------------- fused flash attention (unchanged) -------------------------
__global__ __launch_bounds__(256) void attn_fused_kernel(
    const float* __restrict__ qkv, float* __restrict__ x) {
  __shared__ float Qs[16][36];
  __shared__ float KVs[64][36];
  __shared__ float Osm[16][16][34];

  int t  = threadIdx.x;
  int it = blockIdx.x & 31;
  int h  = (blockIdx.x >> 5) & 7;
  int b  = blockIdx.x >> 8;
  int i0 = it * 16;
  int r  = t >> 4;
  int tx = t & 15;
  int i  = i0 + r;
  int njt = (it >> 2) + 1;

  if (t < 128) {
    int qrow = t >> 3, qd4 = t & 7;
    *(float4*)&Qs[qrow][qd4 * 4] =
        *(const float4*)&qkv[(b * SEQ + i0 + qrow) * 768 + h * 32 + qd4 * 4];
  }
  __syncthreads();
  float4 qv[8];
  #pragma unroll
  for (int d4 = 0; d4 < 8; d4++) qv[d4] = *(float4*)&Qs[r][d4 * 4];

  float s[32];
  #pragma unroll
  for (int z = 0; z < 32; z++) s[z] = -1e30f;

  int kr = t >> 2, kd4 = t & 3;

  #pragma unroll
  for (int jt = 0; jt < 8; jt++) {
    if (jt < njt) {
      int j0 = jt * 64;
      const float* kb = &qkv[(b * SEQ + j0 + kr) * 768 + DMODEL + h * 32];
      *(float4*)&KVs[kr][kd4 * 4]       = *(const float4*)&kb[kd4 * 4];
      *(float4*)&KVs[kr][(kd4 + 4) * 4] = *(const float4*)&kb[(kd4 + 4) * 4];
      __syncthreads();
      #pragma unroll
      for (int q = 0; q < 4; q++) {
        int jl = q * 16 + tx;
        int j  = j0 + jl;
        float acc = 0.f;
        #pragma unroll
        for (int d4 = 0; d4 < 8; d4++) {
          float4 kv = *(float4*)&KVs[jl][d4 * 4];
          acc = fmaf(qv[d4].x, kv.x, acc);
          acc = fmaf(qv[d4].y, kv.y, acc);
          acc = fmaf(qv[d4].z, kv.z, acc);
          acc = fmaf(qv[d4].w, kv.w, acc);
        }
        s[jt * 4 + q] = (j <= i) ? acc * 0.17677669529663687f : -1e30f;
      }
      __syncthreads();
    }
  }

  float mx = -1e30f;
  #pragma unroll
  for (int z = 0; z < 32; z++) mx = fmaxf(mx, s[z]);
  #pragma unroll
  for (int o = 8; o >= 1; o >>= 1) mx = fmaxf(mx, __shfl_xor(mx, o, 16));
  float sum = 0.f;
  #pragma unroll
  for (int z = 0; z < 32; z++) {
    float e = expf(s[z] - mx);
    s[z] = e;
    sum += e;
  }
  #pragma unroll
  for (int o = 8; o >= 1; o >>= 1) sum += __shfl_xor(sum, o, 16);
  float inv = 1.f / sum;
  #pragma unroll
  for (int z = 0; z < 32; z++) s[z] *= inv;

  float o[32];
  #pragma unroll
  for (int z = 0; z < 32; z++) o[z] = 0.f;

  #pragma unroll
  for (int jt = 0; jt < 8; jt++) {
    if (jt < njt) {
      int j0 = jt * 64;
      const float* vb = &qkv[(b * SEQ + j0 + kr) * 768 + 2 * DMODEL + h * 32];
      *(float4*)&KVs[kr][kd4 * 4]       = *(const float4*)&vb[kd4 * 4];
      *(float4*)&KVs[kr][(kd4 + 4) * 4] = *(const float4*)&vb[(kd4 + 4) * 4];
      __syncthreads();
      #pragma unroll
      for (int q = 0; q < 4; q++) {
        int jl = q * 16 + tx;
        float p = s[jt * 4 + q];
        #pragma unroll
        for (int d4 = 0; d4 < 8; d4++) {
          float4 vv = *(float4*)&KVs[jl][d4 * 4];
          o[d4 * 4 + 0] = fmaf(p, vv.x, o[d4 * 4 + 0]);
          o[d4 * 4 + 1] = fmaf(p, vv.y, o[d4 * 4 + 1]);
          o[d4 * 4 + 2] = fmaf(p, vv.z, o[d4 * 4 + 2]);
          o[d4 * 4 + 3] = fmaf(p, vv.w, o[d4 * 4 + 3]);
        }
      }
      __syncthreads();
    }
  }

  #pragma unroll
  for (int d2 = 0; d2 < 16; d2++)
    *(float2*)&Osm[r][tx][d2 * 2] = make_float2(o[d2 * 2], o[d2 * 2 + 1]);
  __syncthreads();
  float2 acc2 = make_float2(0.f, 0.f);
  #pragma unroll
  for (int tx2 = 0; tx2 < 16; tx2++) {
    float2 v = *(float2*)&Osm[r][tx2][tx * 2];
    acc2.x += v.x;
    acc2.y += v.y;
  }
  int base = (b * SEQ + i) * DMODEL + h * 32 + tx * 2;
  float2 old = *(float2*)&x[base];
  old.x += acc2.x;
  old.y += acc2.y;
  *(float2*)&x[base] = old;
}

// ---------------- global standardization ------------------------------------
__global__ __launch_bounds__(256) void reduce1_kernel(
    const float* __restrict__ enc, double* __restrict__ part) {
  int t = threadIdx.x;
  double s = 0.0, q = 0.0;
  for (int i = blockIdx.x * 256 + t; i < 262144; i += 256 * 256) {
    double v = (double)enc[i];
    s += v; q += v * v;
  }
  #pragma unroll
  for (int o = 32; o >= 1; o >>= 1) { s += __shfl_xor(s, o); q += __shfl_xor(q, o); }
  __shared__ double ls[4], lq[4];
  int lane = t & 63, wid = t >> 6;
  if (lane == 0) { ls[wid] = s; lq[wid] = q; }
  __syncthreads();
  if (t == 0) {
    part[blockIdx.x * 2]     = ls[0] + ls[1] + ls[2] + ls[3];
    part[blockIdx.x * 2 + 1] = lq[0] + lq[1] + lq[2] + lq[3];
  }
}

__global__ __launch_bounds__(256) void reduce2_kernel(
    const double* __restrict__ part, float* __restrict__ stats) {
  int t = threadIdx.x;
  double s = part[t * 2], q = part[t * 2 + 1];
  #pragma unroll
  for (int o = 32; o >= 1; o >>= 1) { s += __shfl_xor(s, o); q += __shfl_xor(q, o); }
  __shared__ double ls[4], lq[4];
  int lane = t & 63, wid = t >> 6;
  if (lane == 0) { ls[wid] = s; lq[wid] = q; }
  __syncthreads();
  if (t == 0) {
    double S = ls[0] + ls[1] + ls[2] + ls[3];
    double Q = lq[0] + lq[1] + lq[2] + lq[3];
    double n = 262144.0;
    double mean = S / n;
    double var  = (Q - n * mean * mean) / (n - 1.0);
    stats[0] = (float)mean;
    stats[1] = (float)(1.0 / sqrt(var));
  }
}

__global__ __launch_bounds__(256) void norm4_kernel(
    const float4* __restrict__ enc, const float* __restrict__ stats,
    float4* __restrict__ out) {
  int i = blockIdx.x * 256 + threadIdx.x;
  float mean = stats[0], inv = stats[1];
  float4 v = enc[i];
  v.x = (v.x - mean) * inv + 1e-10f;
  v.y = (v.y - mean) * inv + 1e-10f;
  v.z = (v.z - mean) * inv + 1e-10f;
  v.w = (v.w - mean) * inv + 1e-10f;
  out[i] = v;
}

// ---------------------------------------------------------------------------
extern "C" void kernel_launch(void* const* d_in, const int* in_sizes, int n_in,
                              void* d_out, int out_size, void* d_ws, size_t ws_size,
                              hipStream_t stream) {
  const float* state   = (const float*)d_in[0];
  const float* conv_w1 = (const float*)d_in[1];
  const float* conv_b1 = (const float*)d_in[2];
  const float* conv_w2 = (const float*)d_in[3];
  const float* conv_b2 = (const float*)d_in[4];
  const float* conv_w3 = (const float*)d_in[5];
  const float* conv_b3 = (const float*)d_in[6];
  const float* pre_w   = (const float*)d_in[7];
  const float* pre_b   = (const float*)d_in[8];
  const float* pos_w   = (const float*)d_in[9];
  const float* ln1_g   = (const float*)d_in[10];
  const float* ln1_b   = (const float*)d_in[11];
  const float* enc_w   = (const float*)d_in[12];
  const float* enc_bi  = (const float*)d_in[13];
  const float* ln2_g   = (const float*)d_in[14];
  const float* ln2_b   = (const float*)d_in[15];
  const float* ffn_w1  = (const float*)d_in[16];
  const float* ffn_b1  = (const float*)d_in[17];
  const float* ffn_w2  = (const float*)d_in[18];
  const float* ffn_b2  = (const float*)d_in[19];
  const float* emb_w   = (const float*)d_in[20];
  const float* emb_b   = (const float*)d_in[21];
  float* out = (float*)d_out;

  // workspace layout (cursor-based, 256B aligned); ws observed ~540+ MB
  char* p = (char*)d_ws;
  auto alloc = [&](size_t bytes) {
    char* r = p;
    p += (bytes + 255) & ~(size_t)255;
    return r;
  };
  float* c1c = (float*)alloc((size_t)1024 * 46080 * 4);   // 188.7 MB
  float* c2c = (float*)alloc((size_t)1024 * 11520 * 4);   // 47.2 MB
  float* c3  = (float*)alloc(11796480);
  unsigned short* c3h  = (unsigned short*)alloc(5898240);
  unsigned short* c3l  = (unsigned short*)alloc(5898240);
  unsigned short* preTh = (unsigned short*)alloc(1474560);
  unsigned short* preTl = (unsigned short*)alloc(1474560);
  unsigned short* encTh = (unsigned short*)alloc(1572864);
  unsigned short* encTl = (unsigned short*)alloc(1572864);
  unsigned short* f1Th  = (unsigned short*)alloc(2097152);
  unsigned short* f1Tl  = (unsigned short*)alloc(2097152);
  unsigned short* f2Th  = (unsigned short*)alloc(2097152);
  unsigned short* f2Tl  = (unsigned short*)alloc(2097152);
  unsigned short* embTh = (unsigned short*)alloc(131072);
  unsigned short* embTl = (unsigned short*)alloc(131072);
  float* x    = (float*)alloc(1048576);
  unsigned short* xnh = (unsigned short*)alloc(524288);
  unsigned short* xnl = (unsigned short*)alloc(524288);
  unsigned short* xbh = (unsigned short*)alloc(524288);
  unsigned short* xbl = (unsigned short*)alloc(524288);
  float* qkv  = (float*)alloc(3145728);
  unsigned short* h1h = (unsigned short*)alloc(2097152);
  unsigned short* h1l = (unsigned short*)alloc(2097152);
  unsigned short* xfh = (unsigned short*)alloc(524288);
  unsigned short* xfl = (unsigned short*)alloc(524288);
  float* encb = (float*)alloc(1048576);
  double* part = (double*)alloc(4096);
  float* stats = (float*)alloc(256);

  // ---- weight prep (bf16 split + transpose), once per call ----
  tcvt_kernel<<<dim3(90, 8, 1), 256, 0, stream>>>(pre_w, preTh, preTl, 2880, 256);
  tcvt_kernel<<<dim3(8, 24, 4), 256, 0, stream>>>(enc_w, encTh, encTl, 256, 768);
  tcvt_kernel<<<dim3(8, 32, 4), 256, 0, stream>>>(ffn_w1, f1Th, f1Tl, 256, 1024);
  tcvt_kernel<<<dim3(32, 8, 4), 256, 0, stream>>>(ffn_w2, f2Th, f2Tl, 1024, 256);
  tcvt_kernel<<<dim3(8, 8, 1), 256, 0, stream>>>(emb_w, embTh, embTl, 256, 256);

  // ---- convs (LDS-staged, full batch) ----
  conv1_lds_kernel<<<12288, 256, 0, stream>>>(state, conv_w1, conv_b1, c1c);
  conv2_lds_kernel<<<6144, 256, 0, stream>>>(c1c, conv_w2, conv_b2, c2c);
  conv3_lds_kernel<<<1024, 192, 0, stream>>>(c2c, conv_w3, conv_b3, c3);
  cvtpair_kernel<<<2880, 256, 0, stream>>>((const float4*)c3, c3h, c3l);

  // ---- pre projection: x = pre_b + pos, += c3 @ pre_w (split-K S=5) ----
  initpre4_kernel<<<256, 256, 0, stream>>>(
      (float4*)x, (const float4*)pre_b, (const float4*)pos_w);
  gemm_mfma_kernel<2><<<dim3(2, 8, 5), 256, 0, stream>>>(
      c3h, c3l, preTh, preTl, nullptr, x, nullptr, nullptr,
      1024, 256, 2880, 576);

  for (int k = 0; k < 4; k++) {
    ln1_bf_kernel<<<256, 256, 0, stream>>>(x, ln1_g + k * 256, ln1_b + k * 256,
                                           xnh, xnl);
    gemm_mfma_kernel<0><<<dim3(6, 8, 1), 256, 0, stream>>>(
        xnh, xnl, encTh + (size_t)k * 196608, encTl + (size_t)k * 196608,
        enc_bi + k * 768, qkv, nullptr, nullptr, 1024, 768, 256, 256);
    attn_fused_kernel<<<512, 256, 0, stream>>>(qkv, x);
    ln2_bf_kernel<<<256, 256, 0, stream>>>(x, ln2_g + k * 256, ln2_b + k * 256,
                                           xbh, xbl);
    gemm_mfma_kernel<1><<<dim3(8, 8, 1), 256, 0, stream>>>(
        xbh, xbl, f1Th + (size_t)k * 262144, f1Tl + (size_t)k * 262144,
        ffn_b1 + k * 1024, nullptr, h1h, h1l, 1024, 1024, 256, 256);
    addbias4_kernel<<<256, 256, 0, stream>>>(
        (float4*)x, (const float4*)(ffn_b2 + k * 256));
    gemm_mfma_kernel<2><<<dim3(2, 8, 4), 256, 0, stream>>>(
        h1h, h1l, f2Th + (size_t)k * 262144, f2Tl + (size_t)k * 262144,
        nullptr, x, nullptr, nullptr, 1024, 256, 1024, 256);
  }

  // ---- final projection ----
  cvtpair_kernel<<<256, 256, 0, stream>>>((const float4*)x, xfh, xfl);
  gemm_mfma_kernel<0><<<dim3(2, 8, 1), 256, 0, stream>>>(
      xfh, xfl, embTh, embTl, emb_b, encb, nullptr, nullptr,
      1024, 256, 256, 256);

  reduce1_kernel<<<256, 256, 0, stream>>>(encb, part);
  reduce2_kernel<<<1, 256, 0, stream>>>(part, stats);
  norm4_kernel<<<256, 256, 0, stream>>>((const float4*)encb, stats, (float4*)out);
}